// Round 6
// baseline (279.060 us; speedup 1.0000x reference)
//
#include <hip/hip_runtime.h>
#include <math.h>

#define Hd 256
#define Wd 256
#define Cd 128
#define BIGV 1.0e9f

static __device__ __forceinline__ float softplus_f(float x) {
    return fmaxf(x, 0.0f) + log1pf(expf(-fabsf(x)));
}

// ---------------------------------------------------------------------------
// Kernel 1: per-pixel fused feature work.
// 16x8 core per block, 128 threads, grid 512 -> 2 blocks/CU (block-level
// overlap hides staging latency). 18x10 halo, 32-ch chunks in LDS planes.
// ---------------------------------------------------------------------------
#define TW 16
#define TH 8
#define HWC 18            // halo cols
#define HHR 10            // halo rows
#define PXN 180           // 18*10
#define SP  181           // plane stride
#define CHUNK 32

__global__ __launch_bounds__(128) void k_pixel(
    const float* __restrict__ feat,
    const float* __restrict__ w1, const float* __restrict__ b1,
    const float* __restrict__ w2, const float* __restrict__ b2,
    const int*   __restrict__ endn,
    float* __restrict__ out,
    float* __restrict__ costP,
    float* __restrict__ geoG, float* __restrict__ varG,
    float* __restrict__ omgG, float* __restrict__ absG)
{
    __shared__ float  stage[CHUNK * SP];   // 23.2 KB
    __shared__ float4 w1L[Cd * 8];         // 16 KB
    __shared__ float  normL[PXN];
    __shared__ float  endfL[64];

    const int t  = threadIdx.x;
    const int r0 = blockIdx.y * TH;
    const int c0 = blockIdx.x * TW;

    for (int i = t; i < Cd * 8; i += 128) w1L[i] = ((const float4*)w1)[i];
    if (t < 64) {
        int ep = endn[0] * Wd + endn[1];
        endfL[t] = feat[ep * Cd + t];
    }

    const int lr = t >> 4, lc = t & 15;          // lr 0..7, lc 0..15
    const int r = r0 + lr, c = c0 + lc;
    const int px0 = (lr + 1) * HWC + (lc + 1);

    float4 hv[8];
#pragma unroll
    for (int j = 0; j < 8; ++j) hv[j] = make_float4(0.f, 0.f, 0.f, 0.f);
    float dotv[8];
#pragma unroll
    for (int j = 0; j < 8; ++j) dotv[j] = 0.0f;
    float gm_acc = 0.0f, var_acc = 0.0f, abs_acc = 0.0f;

    for (int ch0 = 0; ch0 < Cd; ch0 += CHUNK) {
        __syncthreads();   // protect stage (and w1L on first pass)
        for (int i = t; i < PXN * 8; i += 128) {
            int px = i >> 3, f4 = i & 7;
            int pr = px / HWC;
            int pc = px - pr * HWC;
            int gr = r0 - 1 + pr, gc = c0 - 1 + pc;
            float4 v = make_float4(0.f, 0.f, 0.f, 0.f);
            if ((unsigned)gr < Hd && (unsigned)gc < Wd) {
                v = *reinterpret_cast<const float4*>(
                        &feat[(((gr << 8) + gc) * Cd) + ch0 + (f4 << 2)]);
            }
            int chb = f4 << 2;
            stage[(chb + 0) * SP + px] = v.x;
            stage[(chb + 1) * SP + px] = v.y;
            stage[(chb + 2) * SP + px] = v.z;
            stage[(chb + 3) * SP + px] = v.w;
        }
        __syncthreads();
        for (int px = t; px < PXN; px += 128) {
            float s = 0.0f;
#pragma unroll
            for (int ch = 0; ch < CHUNK; ++ch) {
                float v = stage[ch * SP + px];
                s = fmaf(v, v, s);
            }
            if (ch0 == 0) normL[px] = s; else normL[px] += s;
        }
        const bool is_hf = (ch0 >= 64);
        for (int ch = 0; ch < CHUNK; ++ch) {
            const float* pl = stage + ch * SP + px0;
            float x  = pl[0];
            float n0 = pl[-HWC - 1], n1 = pl[-HWC], n2 = pl[-HWC + 1];
            float n3 = pl[-1],                      n4 = pl[1];
            float n5 = pl[HWC - 1],  n6 = pl[HWC],  n7 = pl[HWC + 1];

            float gx = (n2 + 2.f * n4 + n7) - (n0 + 2.f * n3 + n5);
            float gy = (n5 + 2.f * n6 + n7) - (n0 + 2.f * n1 + n2);
            gm_acc += sqrtf(gx * gx + gy * gy);

            if (is_hf) {
                float s1 = x + n0 + n1 + n2 + n3 + n4 + n5 + n6 + n7;
                float s2 = x*x + n0*n0 + n1*n1 + n2*n2 + n3*n3 + n4*n4
                         + n5*n5 + n6*n6 + n7*n7;
                float m = s1 * (1.0f / 9.0f);
                var_acc += s2 * (1.0f / 9.0f) - m * m;
            } else {
                float dlf = x - endfL[ch0 + ch];
                abs_acc = fmaf(dlf, dlf, abs_acc);
            }

            dotv[0] = fmaf(x, n0, dotv[0]);
            dotv[1] = fmaf(x, n1, dotv[1]);
            dotv[2] = fmaf(x, n2, dotv[2]);
            dotv[3] = fmaf(x, n3, dotv[3]);
            dotv[4] = fmaf(x, n4, dotv[4]);
            dotv[5] = fmaf(x, n5, dotv[5]);
            dotv[6] = fmaf(x, n6, dotv[6]);
            dotv[7] = fmaf(x, n7, dotv[7]);

            const float4* __restrict__ wr4 = &w1L[(ch0 + ch) << 3];
#pragma unroll
            for (int j4 = 0; j4 < 8; ++j4) {
                float4 wv = wr4[j4];                  // broadcast ds_read_b128
                hv[j4].x = fmaf(x, wv.x, hv[j4].x);
                hv[j4].y = fmaf(x, wv.y, hv[j4].y);
                hv[j4].z = fmaf(x, wv.z, hv[j4].z);
                hv[j4].w = fmaf(x, wv.w, hv[j4].w);
            }
        }
    }
    __syncthreads();   // normL complete before neighbor reads

    const int p = (r << 8) + c;
    float geo  = gm_acc * (1.0f / 128.0f);
    float absp = sqrtf(abs_acc);
    float o = b2[0];
#pragma unroll
    for (int j4 = 0; j4 < 8; ++j4) {
#pragma unroll
        for (int cc = 0; cc < 4; ++cc) {
            int j = (j4 << 2) + cc;
            float hj = fmaxf(((const float*)&hv[j4])[cc] + b1[j], 0.0f);
            o = fmaf(hj, w2[j], o);
        }
    }
    float omg = 1.0f / (1.0f + expf(-o));
    geoG[p] = geo; varG[p] = var_acc; omgG[p] = omg; absG[p] = absp;

    float np = fmaxf(sqrtf(normL[px0]), 1e-12f);
    const int drr[8] = {-1,-1,-1, 0, 0, 1, 1, 1};
    const int dcc[8] = {-1, 0, 1,-1, 1,-1, 0, 1};
    const int nof[8] = {-HWC-1,-HWC,-HWC+1,-1,1,HWC-1,HWC,HWC+1};
#pragma unroll
    for (int j = 0; j < 8; ++j) {
        int nr = r + drr[j], nc = c + dcc[j];
        float cj;
        if ((unsigned)nr < Hd && (unsigned)nc < Wd) {
            float nn = fmaxf(sqrtf(normL[px0 + nof[j]]), 1e-12f);
            cj = 1.0f - dotv[j] / (np * nn);
        } else {
            cj = BIGV;
        }
        costP[(j << 16) + p] = cj;
        out[p * 10 + 1 + j]  = cj;
    }
}

// ---------------------------------------------------------------------------
// Kernel 2: persistent distance map, tagged-data sync, BATCHED polling.
// Heuristic-combine folded into the startup (visibility via kernel boundary).
// Each thread's 3 halo cells are polled in parallel each retry round ->
// one MALL round trip instead of three serial ones.
// ---------------------------------------------------------------------------
#define TSTR 35

__global__ __launch_bounds__(256) void k_dist(
    const float* __restrict__ costP, const int* __restrict__ startn,
    const float* __restrict__ geoG, const float* __restrict__ varG,
    const float* __restrict__ omgG, const float* __restrict__ absG,
    const float* __restrict__ dlt, const float* __restrict__ gmm,
    const float* __restrict__ bta, const int* __restrict__ endn,
    float* __restrict__ out, unsigned long long* coreBuf)
{
    __shared__ float D[2][34 * TSTR];
    const int t  = threadIdx.x;
    const int tc = t & 31;
    const int q  = t >> 5;
    const int rbase = q << 2;
    const int bx = blockIdx.x, by = blockIdx.y;
    const int b  = (by << 4) + bx;
    const int r0 = by << 4, c0 = bx << 4;       // core origin; tile origin -8

    // ---- folded heuristic combine for this block's 16x16 core (1 px/thread)
    {
        int gp = ((r0 + (t >> 4)) << 8) + (c0 + (t & 15));
        float dd = softplus_f(dlt[0]);
        float gg = softplus_f(gmm[0]);
        float bb2 = softplus_f(bta[0]);
        float vend = varG[endn[0] * Wd + endn[1]];
        float omg  = omgG[gp];
        float heur = dd * geoG[gp] + omg * gg * (vend - varG[gp])
                   + (1.0f - omg) * bb2 * absG[gp];
        out[gp * 10] = fmaxf(heur, 0.0f);
    }

    const int sp = startn[0] * Wd + startn[1];

    for (int i = t; i < 2 * 34 * TSTR; i += 256) (&D[0][0])[i] = BIGV;
    __syncthreads();

    // ---- costs into registers (once) + initial state s0
    float cR[4][8];
#pragma unroll
    for (int i = 0; i < 4; ++i) {
        int tr = rbase + i;
        int gr = r0 - 8 + tr, gc = c0 - 8 + tc;
        bool in = ((unsigned)gr < Hd) && ((unsigned)gc < Wd);
        int p = (gr << 8) + gc;
#pragma unroll
        for (int j = 0; j < 8; ++j)
            cR[i][j] = in ? costP[(j << 16) + p] : BIGV;
        D[0][(tr + 1) * TSTR + tc + 1] = (in && p == sp) ? 0.0f : BIGV;
    }

    // ---- precompute this thread's 3 halo-cell descriptors (phase-invariant)
    unsigned long long* hptr[3];   // slot base (without parity term resolved)
    int hoff[3];                   // coreBuf offset within neighbor slot pair
    int hlds[3];
#pragma unroll
    for (int k = 0; k < 3; ++k) {
        int i = t + (k << 8);
        int hr, hc;
        if (i < 256)      { hr = (i >> 5) - 8;        hc = (i & 31) - 8; }
        else if (i < 512) { int k2 = i - 256; hr = 16 + (k2 >> 5); hc = (k2 & 31) - 8; }
        else              { int k2 = i - 512; hr = k2 >> 4;
                            int m2 = k2 & 15; hc = (m2 < 8) ? m2 - 8 : m2 + 8; }
        int dbx = (hc < 0) ? -1 : (hc >= 16 ? 1 : 0);
        int dby = (hr < 0) ? -1 : (hr >= 16 ? 1 : 0);
        int nbx = bx + dbx, nby = by + dby;
        hlds[k] = (hr + 9) * TSTR + (hc + 9);
        if ((unsigned)nbx < 16 && (unsigned)nby < 16) {
            int nb = (nby << 4) + nbx;
            hptr[k] = &coreBuf[(nb << 9) + ((hr & 15) << 4) + (hc & 15)];
        } else {
            hptr[k] = nullptr;
            D[0][hlds[k]] = BIGV;      // stays BIG for all phases
        }
    }
    __syncthreads();

    for (int j = 0; j < 32; ++j) {
        if (j > 0) {
            // batched poll: issue all pending tagged loads each round
            const int parOfs = (j & 1) << 8;
            bool need[3];
#pragma unroll
            for (int k = 0; k < 3; ++k) need[k] = (hptr[k] != nullptr);
            int rounds = 0;
            for (;;) {
                unsigned long long u[3];
                bool acq = ((rounds & 255) == 255);
#pragma unroll
                for (int k = 0; k < 3; ++k) {
                    if (need[k]) {
                        u[k] = acq
                            ? __hip_atomic_load(hptr[k] + parOfs, __ATOMIC_ACQUIRE,
                                                __HIP_MEMORY_SCOPE_AGENT)
                            : __hip_atomic_load(hptr[k] + parOfs, __ATOMIC_RELAXED,
                                                __HIP_MEMORY_SCOPE_AGENT);
                    }
                }
                bool any = false;
#pragma unroll
                for (int k = 0; k < 3; ++k) {
                    if (need[k]) {
                        if ((int)(u[k] >> 32) == j) {
                            D[0][hlds[k]] = __uint_as_float((unsigned int)u[k]);
                            need[k] = false;
                        } else any = true;
                    }
                }
                if (!any) break;
                __builtin_amdgcn_s_sleep(1);
                ++rounds;
            }
            __syncthreads();
        }
        // ---- 8 exact Jacobi iterations, shrinking active margin
#pragma unroll
        for (int it = 0; it < 8; ++it) {
            const float* __restrict__ Dc = D[it & 1];
            float*       __restrict__ Dn = D[1 - (it & 1)];
            const int m = 7 - it;
            if (rbase + 3 >= 8 - m && rbase <= 23 + m) {
                int idx = rbase * TSTR + tc + 1;
                float a = Dc[idx - 1], bb = Dc[idx], cv = Dc[idx + 1];
                idx += TSTR;
                float d = Dc[idx - 1], e = Dc[idx], f = Dc[idx + 1];
#pragma unroll
                for (int i = 0; i < 4; ++i) {
                    idx += TSTR;
                    float g = Dc[idx - 1], h = Dc[idx], i2 = Dc[idx + 1];
                    float best = e;
                    best = fminf(best, a  + cR[i][0]);
                    best = fminf(best, bb + cR[i][1]);
                    best = fminf(best, cv + cR[i][2]);
                    best = fminf(best, d  + cR[i][3]);
                    best = fminf(best, f  + cR[i][4]);
                    best = fminf(best, g  + cR[i][5]);
                    best = fminf(best, h  + cR[i][6]);
                    best = fminf(best, i2 + cR[i][7]);
                    Dn[idx - TSTR] = best;
                    a = d; bb = e; cv = f;
                    d = g; e = h; f = i2;
                }
            }
            __syncthreads();
        }
        // result (s_{j+1}) is back in D[0]; publish tagged core (fire-and-forget)
        if (j < 31) {
            const int parOfs = ((j + 1) & 1) << 8;
            if (tc >= 8 && tc < 24 && q >= 2 && q < 6) {
#pragma unroll
                for (int i = 0; i < 4; ++i) {
                    int tr = rbase + i;
                    float v = D[0][(tr + 1) * TSTR + tc + 1];
                    unsigned long long u =
                        (((unsigned long long)(unsigned int)(j + 1)) << 32)
                        | (unsigned long long)__float_as_uint(v);
                    __hip_atomic_store(
                        &coreBuf[(b << 9) + parOfs + ((tr - 8) << 4) + (tc - 8)],
                        u, __ATOMIC_RELAXED, __HIP_MEMORY_SCOPE_AGENT);
                }
            }
        } else {
            if (tc >= 8 && tc < 24 && q >= 2 && q < 6) {
#pragma unroll
                for (int i = 0; i < 4; ++i) {
                    int tr = rbase + i;
                    int gr = r0 - 8 + tr, gc = c0 - 8 + tc;
                    float v = D[0][(tr + 1) * TSTR + tc + 1];
                    out[((gr << 8) + gc) * 10 + 9] = fminf(v, BIGV);
                }
            }
        }
    }
}

// ---------------------------------------------------------------------------
extern "C" void kernel_launch(void* const* d_in, const int* in_sizes, int n_in,
                              void* d_out, int out_size, void* d_ws, size_t ws_size,
                              hipStream_t stream)
{
    const float* feat  = (const float*)d_in[0];
    const float* dlt   = (const float*)d_in[1];
    const float* gmm   = (const float*)d_in[2];
    const float* bta   = (const float*)d_in[3];
    const float* w1    = (const float*)d_in[4];
    const float* b1    = (const float*)d_in[5];
    const float* w2    = (const float*)d_in[6];
    const float* b2    = (const float*)d_in[7];
    const int*   startn= (const int*)d_in[8];
    const int*   endn  = (const int*)d_in[9];
    float* out = (float*)d_out;
    float* ws  = (float*)d_ws;

    float* costP = ws;                          // 8 planes of 65536 floats
    float* geoG  = ws + 8 * 65536;
    float* varG  = ws + 9 * 65536;
    float* omgG  = ws + 10 * 65536;
    float* absG  = ws + 11 * 65536;
    unsigned long long* coreBuf =
        (unsigned long long*)(ws + 12 * 65536);  // 256 blk x 2 par x 256 x 8B

    dim3 gpix(16, 32);                           // 16x8 cores
    k_pixel<<<gpix, 128, 0, stream>>>(feat, w1, b1, w2, b2, endn,
                                      out, costP, geoG, varG, omgG, absG);
    dim3 g16(16, 16);
    k_dist<<<g16, 256, 0, stream>>>(costP, startn, geoG, varG, omgG, absG,
                                    dlt, gmm, bta, endn, out, coreBuf);
}

// Round 7
// 257.213 us; speedup vs baseline: 1.0849x; 1.0849x over previous
//
#include <hip/hip_runtime.h>
#include <math.h>

#define Hd 256
#define Wd 256
#define Cd 128
#define BIGV 1.0e9f

static __device__ __forceinline__ float softplus_f(float x) {
    return fmaxf(x, 0.0f) + log1pf(expf(-fabsf(x)));
}

// ---------------------------------------------------------------------------
// Kernel 1: per-pixel fused feature work + heuristic (combine folded in).
// 16x16 pixel tile per block (256 threads), 18x18 halo staging, 32-ch chunks
// in LDS planes (stride 325). Weights as float4 broadcast reads. Each block
// redundantly computes vend (end-node hf variance) from 9 coalesced loads.
// ---------------------------------------------------------------------------
#define TILE 16
#define HPX 18
#define PXN 324          // 18*18
#define SP  325          // padded plane stride
#define CHUNK 32

__global__ __launch_bounds__(256) void k_pixel(
    const float* __restrict__ feat,
    const float* __restrict__ w1, const float* __restrict__ b1,
    const float* __restrict__ w2, const float* __restrict__ b2,
    const float* __restrict__ dlt, const float* __restrict__ gmm,
    const float* __restrict__ bta, const int* __restrict__ endn,
    float* __restrict__ out, float* __restrict__ costP)
{
    __shared__ float  stage[CHUNK * SP];   // 41.6 KB
    __shared__ float4 w1L[Cd * 8];         // 16 KB
    __shared__ float  normL[PXN];
    __shared__ float  endfL[64];
    __shared__ float  vendL[64];
    __shared__ float  vendS;

    const int t  = threadIdx.x;
    const int r0 = blockIdx.y * TILE;
    const int c0 = blockIdx.x * TILE;

    for (int i = t; i < Cd * 8; i += 256) w1L[i] = ((const float4*)w1)[i];
    const int er = endn[0], ec = endn[1];
    if (t < 64) {
        endfL[t] = feat[(er * Wd + ec) * Cd + t];   // lf channels 0..63
        // end-node hf variance contribution, channel 64+t (zero-padded pool)
        float s1 = 0.0f, s2 = 0.0f;
#pragma unroll
        for (int dr = -1; dr <= 1; ++dr)
#pragma unroll
            for (int dc = -1; dc <= 1; ++dc) {
                int gr = er + dr, gc = ec + dc;
                if ((unsigned)gr < Hd && (unsigned)gc < Wd) {
                    float x = feat[((gr << 8) + gc) * Cd + 64 + t];
                    s1 += x; s2 = fmaf(x, x, s2);
                }
            }
        float m = s1 * (1.0f / 9.0f);
        vendL[t] = s2 * (1.0f / 9.0f) - m * m;
    }

    const int lr = t >> 4, lc = t & 15;
    const int r = r0 + lr, c = c0 + lc;
    const int px0 = (lr + 1) * HPX + (lc + 1);

    float4 hv[8];
#pragma unroll
    for (int j = 0; j < 8; ++j) hv[j] = make_float4(0.f, 0.f, 0.f, 0.f);
    float dotv[8];
#pragma unroll
    for (int j = 0; j < 8; ++j) dotv[j] = 0.0f;
    float gm_acc = 0.0f, var_acc = 0.0f, abs_acc = 0.0f;

    for (int ch0 = 0; ch0 < Cd; ch0 += CHUNK) {
        __syncthreads();   // protect stage (and w1L/endfL on first pass)
        for (int i = t; i < PXN * 8; i += 256) {
            int px = i >> 3, f4 = i & 7;
            int pr = px / HPX;
            int pc = px - pr * HPX;
            int gr = r0 - 1 + pr, gc = c0 - 1 + pc;
            float4 v = make_float4(0.f, 0.f, 0.f, 0.f);
            if ((unsigned)gr < Hd && (unsigned)gc < Wd) {
                v = *reinterpret_cast<const float4*>(
                        &feat[(((gr << 8) + gc) * Cd) + ch0 + (f4 << 2)]);
            }
            int chb = f4 << 2;
            stage[(chb + 0) * SP + px] = v.x;
            stage[(chb + 1) * SP + px] = v.y;
            stage[(chb + 2) * SP + px] = v.z;
            stage[(chb + 3) * SP + px] = v.w;
        }
        __syncthreads();
        for (int px = t; px < PXN; px += 256) {
            float s = 0.0f;
#pragma unroll
            for (int ch = 0; ch < CHUNK; ++ch) {
                float v = stage[ch * SP + px];
                s = fmaf(v, v, s);
            }
            if (ch0 == 0) normL[px] = s; else normL[px] += s;
        }
        const bool is_hf = (ch0 >= 64);
        for (int ch = 0; ch < CHUNK; ++ch) {
            const float* pl = stage + ch * SP + px0;
            float x  = pl[0];
            float n0 = pl[-HPX - 1], n1 = pl[-HPX], n2 = pl[-HPX + 1];
            float n3 = pl[-1],                      n4 = pl[1];
            float n5 = pl[HPX - 1],  n6 = pl[HPX],  n7 = pl[HPX + 1];

            float gx = (n2 + 2.f * n4 + n7) - (n0 + 2.f * n3 + n5);
            float gy = (n5 + 2.f * n6 + n7) - (n0 + 2.f * n1 + n2);
            gm_acc += sqrtf(gx * gx + gy * gy);

            if (is_hf) {
                float s1 = x + n0 + n1 + n2 + n3 + n4 + n5 + n6 + n7;
                float s2 = x*x + n0*n0 + n1*n1 + n2*n2 + n3*n3 + n4*n4
                         + n5*n5 + n6*n6 + n7*n7;
                float m = s1 * (1.0f / 9.0f);
                var_acc += s2 * (1.0f / 9.0f) - m * m;
            } else {
                float dlf = x - endfL[ch0 + ch];
                abs_acc = fmaf(dlf, dlf, abs_acc);
            }

            dotv[0] = fmaf(x, n0, dotv[0]);
            dotv[1] = fmaf(x, n1, dotv[1]);
            dotv[2] = fmaf(x, n2, dotv[2]);
            dotv[3] = fmaf(x, n3, dotv[3]);
            dotv[4] = fmaf(x, n4, dotv[4]);
            dotv[5] = fmaf(x, n5, dotv[5]);
            dotv[6] = fmaf(x, n6, dotv[6]);
            dotv[7] = fmaf(x, n7, dotv[7]);

            const float4* __restrict__ wr4 = &w1L[(ch0 + ch) << 3];
#pragma unroll
            for (int j4 = 0; j4 < 8; ++j4) {
                float4 wv = wr4[j4];                  // broadcast ds_read_b128
                hv[j4].x = fmaf(x, wv.x, hv[j4].x);
                hv[j4].y = fmaf(x, wv.y, hv[j4].y);
                hv[j4].z = fmaf(x, wv.z, hv[j4].z);
                hv[j4].w = fmaf(x, wv.w, hv[j4].w);
            }
        }
    }
    __syncthreads();   // normL complete

    // ---- vend reduction (wave 0) then broadcast
    if (t < 64) {
        float v = vendL[t];
#pragma unroll
        for (int o = 32; o > 0; o >>= 1) v += __shfl_down(v, o, 64);
        if (t == 0) vendS = v;
    }
    __syncthreads();
    const float vend = vendS;

    // ---- finalize
    const int p = (r << 8) + c;
    float geo  = gm_acc * (1.0f / 128.0f);
    float absp = sqrtf(abs_acc);
    float o = b2[0];
#pragma unroll
    for (int j4 = 0; j4 < 8; ++j4) {
#pragma unroll
        for (int cc = 0; cc < 4; ++cc) {
            int j = (j4 << 2) + cc;
            float hj = fmaxf(((const float*)&hv[j4])[cc] + b1[j], 0.0f);
            o = fmaf(hj, w2[j], o);
        }
    }
    float omg = 1.0f / (1.0f + expf(-o));
    float dS = softplus_f(dlt[0]);
    float gS = softplus_f(gmm[0]);
    float bS = softplus_f(bta[0]);
    float heur = dS * geo + omg * gS * (vend - var_acc)
               + (1.0f - omg) * bS * absp;
    out[p * 10] = fmaxf(heur, 0.0f);

    float np = fmaxf(sqrtf(normL[px0]), 1e-12f);
    const int drr[8] = {-1,-1,-1, 0, 0, 1, 1, 1};
    const int dcc[8] = {-1, 0, 1,-1, 1,-1, 0, 1};
    const int nof[8] = {-HPX-1,-HPX,-HPX+1,-1,1,HPX-1,HPX,HPX+1};
#pragma unroll
    for (int j = 0; j < 8; ++j) {
        int nr = r + drr[j], nc = c + dcc[j];
        float cj;
        if ((unsigned)nr < Hd && (unsigned)nc < Wd) {
            float nn = fmaxf(sqrtf(normL[px0 + nof[j]]), 1e-12f);
            cj = 1.0f - dotv[j] / (np * nn);
        } else {
            cj = BIGV;
        }
        costP[(j << 16) + p] = cj;
        out[p * 10 + 1 + j]  = cj;
    }
}

// ---------------------------------------------------------------------------
// Kernel 2: persistent distance map.
// Tagged-data sync, SINGLE buffer, tag >= j acceptance (over-relaxation is
// monotone-safe: result in [d_inf, d_256], threshold 2e7 >> 510 bound).
// Poll loop issues 3 UNCONDITIONAL relaxed loads per round (dummy slot for
// OOB) -> one vmcnt wait per round instead of 3 serial ones.
// All-BIG tiles skip their 8 Jacobi iterations -> blocks ahead of the
// wavefront publish instantly, shortening the critical chain.
// ---------------------------------------------------------------------------
#define TSTR 35

__global__ __launch_bounds__(256) void k_dist(
    const float* __restrict__ costP, const int* __restrict__ startn,
    float* __restrict__ out, unsigned long long* coreBuf)
{
    __shared__ float D[2][34 * TSTR];
    const int t  = threadIdx.x;
    const int tc = t & 31;
    const int q  = t >> 5;
    const int rbase = q << 2;
    const int bx = blockIdx.x, by = blockIdx.y;
    const int b  = (by << 4) + bx;
    const int r0 = by << 4, c0 = bx << 4;       // core origin; tile origin -8

    const int sp = startn[0] * Wd + startn[1];

    for (int i = t; i < 2 * 34 * TSTR; i += 256) (&D[0][0])[i] = BIGV;
    __syncthreads();

    // ---- costs into registers (once) + initial state s0
    float cR[4][8];
#pragma unroll
    for (int i = 0; i < 4; ++i) {
        int tr = rbase + i;
        int gr = r0 - 8 + tr, gc = c0 - 8 + tc;
        bool in = ((unsigned)gr < Hd) && ((unsigned)gc < Wd);
        int p = (gr << 8) + gc;
#pragma unroll
        for (int j = 0; j < 8; ++j)
            cR[i][j] = in ? costP[(j << 16) + p] : BIGV;
        D[0][(tr + 1) * TSTR + tc + 1] = (in && p == sp) ? 0.0f : BIGV;
    }

    // ---- this thread's 3 halo-cell descriptors (phase-invariant)
    unsigned long long* const dummy = coreBuf + 65536;
    unsigned long long* hp[3];
    int  hl[3];
    bool hvld[3];
#pragma unroll
    for (int k = 0; k < 3; ++k) {
        int i = t + (k << 8);
        int hr, hc;
        if (i < 256)      { hr = (i >> 5) - 8;        hc = (i & 31) - 8; }
        else if (i < 512) { int k2 = i - 256; hr = 16 + (k2 >> 5); hc = (k2 & 31) - 8; }
        else              { int k2 = i - 512; hr = k2 >> 4;
                            int m2 = k2 & 15; hc = (m2 < 8) ? m2 - 8 : m2 + 8; }
        int dbx = (hc < 0) ? -1 : (hc >= 16 ? 1 : 0);
        int dby = (hr < 0) ? -1 : (hr >= 16 ? 1 : 0);
        int nbx = bx + dbx, nby = by + dby;
        hl[k] = (hr + 9) * TSTR + (hc + 9);
        bool v = ((unsigned)nbx < 16) && ((unsigned)nby < 16);
        hvld[k] = v;
        hp[k] = v ? &coreBuf[(((nby << 4) + nbx) << 8) + ((hr & 15) << 4) + (hc & 15)]
                  : dummy;
        // invalid cells stay BIGV forever (their costs are BIG -> never change)
    }
    __syncthreads();

    bool myCoreFinite = false;
    const bool isPub = (tc >= 8 && tc < 24 && q >= 2 && q < 6);

    for (int j = 0; j < 32; ++j) {
        bool haloFin = false;
        if (j > 0) {
            bool n0 = hvld[0], n1 = hvld[1], n2 = hvld[2];
            int rounds = 0;
            while (n0 | n1 | n2) {
                bool acq = ((rounds & 255) == 255);
                unsigned long long u0 = acq
                    ? __hip_atomic_load(hp[0], __ATOMIC_ACQUIRE, __HIP_MEMORY_SCOPE_AGENT)
                    : __hip_atomic_load(hp[0], __ATOMIC_RELAXED, __HIP_MEMORY_SCOPE_AGENT);
                unsigned long long u1 =
                      __hip_atomic_load(hp[1], __ATOMIC_RELAXED, __HIP_MEMORY_SCOPE_AGENT);
                unsigned long long u2 =
                      __hip_atomic_load(hp[2], __ATOMIC_RELAXED, __HIP_MEMORY_SCOPE_AGENT);
                if (n0 && (int)(u0 >> 32) >= j) {
                    float v = __uint_as_float((unsigned int)u0);
                    D[0][hl[0]] = v; haloFin |= (v < BIGV); n0 = false;
                }
                if (n1 && (int)(u1 >> 32) >= j) {
                    float v = __uint_as_float((unsigned int)u1);
                    D[0][hl[1]] = v; haloFin |= (v < BIGV); n1 = false;
                }
                if (n2 && (int)(u2 >> 32) >= j) {
                    float v = __uint_as_float((unsigned int)u2);
                    D[0][hl[2]] = v; haloFin |= (v < BIGV); n2 = false;
                }
                if (n0 | n1 | n2) { __builtin_amdgcn_s_sleep(1); ++rounds; }
            }
        }
        int active = __syncthreads_or((int)(haloFin || myCoreFinite || (j == 0)));

        if (active) {
            // ---- 8 exact Jacobi iterations, shrinking active row margin
#pragma unroll
            for (int it = 0; it < 8; ++it) {
                const float* __restrict__ Dc = D[it & 1];
                float*       __restrict__ Dn = D[1 - (it & 1)];
                const int m = 7 - it;
                if (rbase + 3 >= 8 - m && rbase <= 23 + m) {
                    int idx = rbase * TSTR + tc + 1;
                    float a = Dc[idx - 1], bb = Dc[idx], cv = Dc[idx + 1];
                    idx += TSTR;
                    float d = Dc[idx - 1], e = Dc[idx], f = Dc[idx + 1];
#pragma unroll
                    for (int i = 0; i < 4; ++i) {
                        idx += TSTR;
                        float g = Dc[idx - 1], h = Dc[idx], i2 = Dc[idx + 1];
                        float best = e;
                        best = fminf(best, a  + cR[i][0]);
                        best = fminf(best, bb + cR[i][1]);
                        best = fminf(best, cv + cR[i][2]);
                        best = fminf(best, d  + cR[i][3]);
                        best = fminf(best, f  + cR[i][4]);
                        best = fminf(best, g  + cR[i][5]);
                        best = fminf(best, h  + cR[i][6]);
                        best = fminf(best, i2 + cR[i][7]);
                        Dn[idx - TSTR] = best;
                        a = d; bb = e; cv = f;
                        d = g; e = h; f = i2;
                    }
                }
                __syncthreads();
            }
        }
        // s_{8(j+1)} (or unchanged all-BIG) is in D[0]
        if (j < 31) {
            if (isPub) {
                bool fin = false;
#pragma unroll
                for (int i = 0; i < 4; ++i) {
                    int tr = rbase + i;
                    float v = D[0][(tr + 1) * TSTR + tc + 1];
                    fin |= (v < BIGV);
                    unsigned long long u =
                        (((unsigned long long)(unsigned int)(j + 1)) << 32)
                        | (unsigned long long)__float_as_uint(v);
                    __hip_atomic_store(
                        &coreBuf[(b << 8) + ((tr - 8) << 4) + (tc - 8)],
                        u, __ATOMIC_RELAXED, __HIP_MEMORY_SCOPE_AGENT);
                }
                myCoreFinite = fin;
            }
        } else {
            if (isPub) {
#pragma unroll
                for (int i = 0; i < 4; ++i) {
                    int tr = rbase + i;
                    int gr = r0 - 8 + tr, gc = c0 - 8 + tc;
                    float v = D[0][(tr + 1) * TSTR + tc + 1];
                    out[((gr << 8) + gc) * 10 + 9] = fminf(v, BIGV);
                }
            }
        }
    }
}

// ---------------------------------------------------------------------------
extern "C" void kernel_launch(void* const* d_in, const int* in_sizes, int n_in,
                              void* d_out, int out_size, void* d_ws, size_t ws_size,
                              hipStream_t stream)
{
    const float* feat  = (const float*)d_in[0];
    const float* dlt   = (const float*)d_in[1];
    const float* gmm   = (const float*)d_in[2];
    const float* bta   = (const float*)d_in[3];
    const float* w1    = (const float*)d_in[4];
    const float* b1    = (const float*)d_in[5];
    const float* w2    = (const float*)d_in[6];
    const float* b2    = (const float*)d_in[7];
    const int*   startn= (const int*)d_in[8];
    const int*   endn  = (const int*)d_in[9];
    float* out = (float*)d_out;
    float* ws  = (float*)d_ws;

    float* costP = ws;                          // 8 planes of 65536 floats
    unsigned long long* coreBuf =
        (unsigned long long*)(ws + 8 * 65536);  // 65536 cells + 1 dummy, u64

    dim3 g16(16, 16);
    k_pixel<<<g16, 256, 0, stream>>>(feat, w1, b1, w2, b2,
                                     dlt, gmm, bta, endn, out, costP);
    k_dist<<<g16, 256, 0, stream>>>(costP, startn, out, coreBuf);
}